// Round 2
// baseline (365.667 us; speedup 1.0000x reference)
//
#include <hip/hip_runtime.h>

// Problem constants
#define NN 100000      // nodes
#define NE 600000      // edges
#define D  128         // feature dim in (both layers)
#define DOUT2 96
#define NREL 4
#define KREL 512       // NREL * D
#define KCAT 640       // KREL + D
#define SCAN_B 98      // ceil(NN / 1024)

typedef short short8 __attribute__((ext_vector_type(8)));   // 8 bf16
typedef float f32x4  __attribute__((ext_vector_type(4)));
typedef float f32x2  __attribute__((ext_vector_type(2)));

// fp32 -> bf16 round-to-nearest-even (finite inputs)
__device__ __forceinline__ ushort f2bf(float x) {
    unsigned u = __builtin_bit_cast(unsigned, x);
    u += 0x7fffu + ((u >> 16) & 1u);
    return (ushort)(u >> 16);
}
// unpack 2 bf16 (lo,hi of one u32) -> f32x2, for v_pk_fma_f32 accumulate
__device__ __forceinline__ f32x2 bfpair(unsigned u) {
    f32x2 r;
    r.x = __builtin_bit_cast(float, u << 16);
    r.y = __builtin_bit_cast(float, u & 0xffff0000u);
    return r;
}

// ---------------------------------------------------------------------------
// Fused independent prep: zero cnt, zero fill, x->bf16, pack Wcp1, pack Wcp2.
__global__ void prep0(const float* __restrict__ x, ushort* __restrict__ Xb,
                      const float* __restrict__ W1, const float* __restrict__ root1,
                      short* __restrict__ Wp1,
                      const float* __restrict__ W2, const float* __restrict__ root2,
                      short* __restrict__ Wp2,
                      float* __restrict__ cnt, int* __restrict__ fill) {
    int i = blockIdx.x * 256 + threadIdx.x;
    const int S0 = (NN * NREL) / 4;   // 100000 float4 zeros of cnt
    const int S1 = NN / 4;            // 25000 int4 zeros of fill
    const int S2 = (NN * D) / 4;      // 3200000 float4->ushort4 converts
    const int S3 = KCAT * D;          // 81920 pack1 elements
    const int S4 = KCAT * DOUT2;      // 61440 pack2 elements
    if (i < S0) { ((float4*)cnt)[i] = make_float4(0.f, 0.f, 0.f, 0.f); return; }
    i -= S0;
    if (i < S1) { ((int4*)fill)[i] = make_int4(0, 0, 0, 0); return; }
    i -= S1;
    if (i < S2) {
        float4 v = ((const float4*)x)[i];
        ushort4 o;
        o.x = f2bf(v.x); o.y = f2bf(v.y); o.z = f2bf(v.z); o.w = f2bf(v.w);
        ((ushort4*)Xb)[i] = o;
        return;
    }
    i -= S2;
    if (i < S3) {   // Wcp[kq][n][j] = Wcat[kq*8+j][n], BN = 128
        int j = i & 7, rest = i >> 3;
        int n = rest % D, kq = rest / D;
        int k = kq * 8 + j;
        float v = (k < KREL) ? W1[(size_t)k * D + n] : root1[(size_t)(k - KREL) * D + n];
        Wp1[i] = (short)f2bf(v);
        return;
    }
    i -= S3;
    if (i < S4) {   // BN = 96
        int j = i & 7, rest = i >> 3;
        int n = rest % DOUT2, kq = rest / DOUT2;
        int k = kq * 8 + j;
        float v = (k < KREL) ? W2[(size_t)k * DOUT2 + n] : root2[(size_t)(k - KREL) * DOUT2 + n];
        Wp2[i] = (short)f2bf(v);
        return;
    }
}

// ---------------------------------------------------------------------------
// cnt[v][r] = #edges with dst=v, etype=r
__global__ void count_deg(const int* __restrict__ dst,
                          const int* __restrict__ et,
                          float* __restrict__ cnt) {
    int e = blockIdx.x * blockDim.x + threadIdx.x;
    if (e < NE) unsafeAtomicAdd(&cnt[dst[e] * NREL + et[e]], 1.0f);
}

// ---------------------------------------------------------------------------
// Prefix sum of per-node degree -> off[0..NN] (3-kernel scan)
__global__ void scan1(const float* __restrict__ cnt, int* __restrict__ bsum) {
    __shared__ int s[256];
    int tid = threadIdx.x;
    int base = blockIdx.x * 1024 + tid * 4;
    int t = 0;
    for (int i = 0; i < 4; i++) {
        int v = base + i;
        if (v < NN) {
            float4 c = *(const float4*)&cnt[(size_t)v * 4];
            t += (int)(c.x + c.y + c.z + c.w);
        }
    }
    s[tid] = t; __syncthreads();
    for (int o = 128; o > 0; o >>= 1) {
        if (tid < o) s[tid] += s[tid + o];
        __syncthreads();
    }
    if (tid == 0) bsum[blockIdx.x] = s[0];
}

__global__ void scan2(int* __restrict__ bsum) {  // 1 block of 128; exclusive in-place
    __shared__ int s[128];
    int tid = threadIdx.x;
    int mine = (tid < SCAN_B) ? bsum[tid] : 0;
    s[tid] = mine; __syncthreads();
    for (int o = 1; o < 128; o <<= 1) {
        int v = (tid >= o) ? s[tid - o] : 0;
        __syncthreads();
        s[tid] += v;
        __syncthreads();
    }
    if (tid < SCAN_B) bsum[tid] = s[tid] - mine;
}

__global__ void scan3(const float* __restrict__ cnt, const int* __restrict__ bsum,
                      int* __restrict__ off) {
    __shared__ int s[256];
    int tid = threadIdx.x;
    int base = blockIdx.x * 1024 + tid * 4;
    int d[4]; int t = 0;
    for (int i = 0; i < 4; i++) {
        int v = base + i; d[i] = 0;
        if (v < NN) {
            float4 c = *(const float4*)&cnt[(size_t)v * 4];
            d[i] = (int)(c.x + c.y + c.z + c.w);
        }
        t += d[i];
    }
    int mine = t;
    s[tid] = t; __syncthreads();
    for (int o = 1; o < 256; o <<= 1) {
        int v = (tid >= o) ? s[tid - o] : 0;
        __syncthreads();
        s[tid] += v;
        __syncthreads();
    }
    int ex = s[tid] - mine + bsum[blockIdx.x];
    for (int i = 0; i < 4; i++) {
        int v = base + i;
        if (v < NN) { off[v] = ex; ex += d[i]; }
    }
    if (blockIdx.x == 0 && tid == 0) off[NN] = NE;
}

// ---------------------------------------------------------------------------
// Bucket edges by dst; record = { (src<<2)|etype, bitcast(norm) } so the
// fused kernel's inner loop does ONE dwordx2 load per edge and never
// touches cnt / rcp.
__global__ void bucket_edges(const int* __restrict__ src, const int* __restrict__ dst,
                             const int* __restrict__ et, const int* __restrict__ off,
                             int* __restrict__ fill, int2* __restrict__ epk,
                             const float* __restrict__ cnt) {
    int e = blockIdx.x * blockDim.x + threadIdx.x;
    if (e >= NE) return;
    int dn = dst[e];
    int t  = et[e];
    int pos = off[dn] + atomicAdd(&fill[dn], 1);
    float nrm = 1.0f / fmaxf(cnt[dn * NREL + t], 1.0f);   // cnt >= 1 for a real edge
    epk[pos] = make_int2((src[e] << 2) | t, __builtin_bit_cast(int, nrm));
}

// ---------------------------------------------------------------------------
// Fused RGCN layer — block-shared A-tile version.
// Block = 256 threads (4 waves), 32 dst nodes, one 32 KB LDS tile
// [kq16=64][node=32][8 bf16] (MFMA A-frag order), node index XOR-swizzled
// with kq&7 so the staging ds_write_b128 is 2-way (free) instead of 16-way.
//   Phase 1: 16 quarter-wave chains; chain g aggregates nodes v0+g, v0+g+16.
//            8-wide then 4-wide gather batches, clamped 3-slot tail batch;
//            f32x2 (v_pk_fma_f32) accumulate with per-edge precomputed norm.
//   Root MFMAs (global-only operands) run BEFORE the barrier to overlap
//            the chain-imbalance tail.
//   Phase 2 (after one barrier): wave w computes quadrant
//            (m-half = w&1, n-half = w>>1): 16 nodes x NFW*16 cols.
template <int BN, bool RELU, bool OUT_BF16>
__global__ __launch_bounds__(256, 5) void rgcn_fused(
    const ushort* __restrict__ Xb,   // [M,128] bf16
    const int2*  __restrict__ epk,   // [NE] bucketed {(src<<2)|t, norm}
    const int*   __restrict__ off,   // [M+1]
    const short* __restrict__ Wcp,   // [80][BN][8] bf16
    const float* __restrict__ bias,  // [BN]
    void*        __restrict__ Cout,  // [M,BN] bf16 or f32
    int M) {
    constexpr int NFW = (BN / 16 + 1) / 2;   // frags per wave: 4 (BN=128) / 3 (BN=96)
    __shared__ short At[64 * 32 * 8];        // 32 KB

    const int tid  = threadIdx.x;
    const int wave = tid >> 6;
    const int lane = tid & 63;
    const int l    = lane & 15;     // phase1: feat group / phase2: m16
    const int qw   = lane >> 4;     // phase1: quarter / phase2: k-quad q
    const int g    = wave * 4 + qw; // chain id 0..15
    const int v0   = blockIdx.x * 32;

    // ---- phase 1: aggregate 32 nodes (2 per chain) ----
#pragma unroll
    for (int hf = 0; hf < 2; hf++) {
        int nv = g + hf * 16;
        int v  = v0 + nv;           // NN % 32 == 0 -> always < M
        f32x2 acc[4][4];            // [rel][feat-pair]
#pragma unroll
        for (int r = 0; r < 4; r++)
#pragma unroll
            for (int k = 0; k < 4; k++) acc[r][k] = (f32x2)0.0f;

        int e = off[v], end = off[v + 1];

#define EDGE_ACC(PK, SF, XB) {                                              \
        int t_ = (PK) & 3;                                                  \
        float s0_ = (t_ == 0) ? (SF) : 0.0f;                                \
        float s1_ = (t_ == 1) ? (SF) : 0.0f;                                \
        float s2_ = (t_ == 2) ? (SF) : 0.0f;                                \
        float s3_ = (t_ == 3) ? (SF) : 0.0f;                                \
        f32x2 xp_;                                                          \
        xp_ = bfpair((XB).x);                                               \
        acc[0][0] += s0_ * xp_; acc[1][0] += s1_ * xp_;                     \
        acc[2][0] += s2_ * xp_; acc[3][0] += s3_ * xp_;                     \
        xp_ = bfpair((XB).y);                                               \
        acc[0][1] += s0_ * xp_; acc[1][1] += s1_ * xp_;                     \
        acc[2][1] += s2_ * xp_; acc[3][1] += s3_ * xp_;                     \
        xp_ = bfpair((XB).z);                                               \
        acc[0][2] += s0_ * xp_; acc[1][2] += s1_ * xp_;                     \
        acc[2][2] += s2_ * xp_; acc[3][2] += s3_ * xp_;                     \
        xp_ = bfpair((XB).w);                                               \
        acc[0][3] += s0_ * xp_; acc[1][3] += s1_ * xp_;                     \
        acc[2][3] += s2_ * xp_; acc[3][3] += s3_ * xp_; }

        // 8-wide batches: 8 gathers in flight (helps high-degree stragglers)
        for (; e + 7 < end; e += 8) {
            int2 ep[8];
#pragma unroll
            for (int k = 0; k < 8; k++) ep[k] = epk[e + k];
            uint4 xv[8];
#pragma unroll
            for (int k = 0; k < 8; k++)
                xv[k] = *(const uint4*)&Xb[(size_t)(ep[k].x >> 2) * D + l * 8];
#pragma unroll
            for (int k = 0; k < 8; k++)
                EDGE_ACC(ep[k].x, __builtin_bit_cast(float, ep[k].y), xv[k]);
        }
        // 4-wide batch
        for (; e + 3 < end; e += 4) {
            int2 ep[4];
#pragma unroll
            for (int k = 0; k < 4; k++) ep[k] = epk[e + k];
            uint4 xv[4];
#pragma unroll
            for (int k = 0; k < 4; k++)
                xv[k] = *(const uint4*)&Xb[(size_t)(ep[k].x >> 2) * D + l * 8];
#pragma unroll
            for (int k = 0; k < 4; k++)
                EDGE_ACC(ep[k].x, __builtin_bit_cast(float, ep[k].y), xv[k]);
        }
        // clamped tail batch (1..3 edges, zero-scale on clamped slots):
        // all gathers issue together instead of serial per-edge round-trips
        if (e < end) {
            int rem = end - e;
            int ea = e + (rem > 1);
            int eb = e + ((rem > 2) ? 2 : 0);
            int2 e0 = epk[e], e1 = epk[ea], e2 = epk[eb];
            float f0 = __builtin_bit_cast(float, e0.y);
            float f1 = (rem > 1) ? __builtin_bit_cast(float, e1.y) : 0.0f;
            float f2 = (rem > 2) ? __builtin_bit_cast(float, e2.y) : 0.0f;
            uint4 x0 = *(const uint4*)&Xb[(size_t)(e0.x >> 2) * D + l * 8];
            uint4 x1 = *(const uint4*)&Xb[(size_t)(e1.x >> 2) * D + l * 8];
            uint4 x2 = *(const uint4*)&Xb[(size_t)(e2.x >> 2) * D + l * 8];
            EDGE_ACC(e0.x, f0, x0); EDGE_ACC(e1.x, f1, x1); EDGE_ACC(e2.x, f2, x2);
        }
#undef EDGE_ACC

        // stage to LDS in A-frag order: kq16 = r*16 + l, node nv,
        // node index XOR-swizzled by kq&7 (== l&7): write is 2-way, free.
#pragma unroll
        for (int r = 0; r < 4; r++) {
            short8 w;
#pragma unroll
            for (int k = 0; k < 4; k++) {
                w[2 * k]     = (short)f2bf(acc[r][k].x);
                w[2 * k + 1] = (short)f2bf(acc[r][k].y);
            }
            int kq = r * 16 + l;
            *(short8*)&At[(kq * 32 + (nv ^ (kq & 7))) * 8] = w;
        }
    }

    // ---- phase 2 setup ----
    const int m16   = l;
    const int q     = qw;
    const int mt    = wave & 1;                 // m-half (16 nodes)
    const int nbase = (wave >> 1) * NFW * 16;   // n-offset
    f32x4 acc2[NFW];
#pragma unroll
    for (int i = 0; i < NFW; i++) acc2[i] = (f32x4)0.0f;

    // root part first (k = 512..639, global-only operands): overlaps the
    // barrier wait on slow chains instead of idling.
    {
        int rowc = v0 + mt * 16 + m16;
        const ushort* Xrow = Xb + (size_t)rowc * D;
#pragma unroll
        for (int s2 = 0; s2 < 4; s2++) {
            short8 af = *(const short8*)&Xrow[s2 * 32 + q * 8];
            const short* bbase = Wcp + ((size_t)((16 + s2) * 4 + q) * BN + nbase + m16) * 8;
#pragma unroll
            for (int nf = 0; nf < NFW; nf++) {
                short8 bf = *(const short8*)(bbase + nf * 128);
                acc2[nf] = __builtin_amdgcn_mfma_f32_16x16x32_bf16(af, bf, acc2[nf], 0, 0, 0);
            }
        }
    }

    __syncthreads();

    // ---- phase 2: 32x512 @ 512xBN from LDS, one quadrant per wave ----
#pragma unroll 4
    for (int ks = 0; ks < 16; ks++) {
        int kq = ks * 4 + q;
        short8 af = *(const short8*)&At[(kq * 32 + ((mt * 16 + m16) ^ (kq & 7))) * 8];
        const short* bbase = Wcp + ((size_t)kq * BN + nbase + m16) * 8;
#pragma unroll
        for (int nf = 0; nf < NFW; nf++) {
            short8 bf = *(const short8*)(bbase + nf * 128);
            acc2[nf] = __builtin_amdgcn_mfma_f32_16x16x32_bf16(af, bf, acc2[nf], 0, 0, 0);
        }
    }

    // ---- epilogue ----
#pragma unroll
    for (int nf = 0; nf < NFW; nf++) {
        int n = nbase + nf * 16 + m16;
        float b = bias[n];
#pragma unroll
        for (int r = 0; r < 4; r++) {
            int m = v0 + mt * 16 + q * 4 + r;
            float vv = acc2[nf][r] + b;
            if (RELU) vv = fmaxf(vv, 0.0f);
            if (OUT_BF16) ((ushort*)Cout)[(size_t)m * BN + n] = f2bf(vv);
            else          ((float*)Cout)[(size_t)m * BN + n]  = vv;
        }
    }
}

// ---------------------------------------------------------------------------
extern "C" void kernel_launch(void* const* d_in, const int* in_sizes, int n_in,
                              void* d_out, int out_size, void* d_ws, size_t ws_size,
                              hipStream_t stream) {
    const float* x     = (const float*)d_in[0];
    const int*   ei    = (const int*)d_in[1];
    const int*   et    = (const int*)d_in[2];
    const float* W1    = (const float*)d_in[3];
    const float* root1 = (const float*)d_in[4];
    const float* b1    = (const float*)d_in[5];
    const float* W2    = (const float*)d_in[6];
    const float* root2 = (const float*)d_in[7];
    const float* b2    = (const float*)d_in[8];
    const int* srcp = ei;
    const int* dstp = ei + NE;
    float* out = (float*)d_out;

    // Workspace layout (all segments 16-B aligned)
    short*  Wp1  = (short*)d_ws;                          // 640*128 bf16
    short*  Wp2  = Wp1 + (size_t)KCAT * D;                // 640*96  bf16
    ushort* Xb   = (ushort*)(Wp2 + (size_t)KCAT * DOUT2); // NN*128 bf16
    ushort* h    = Xb + (size_t)NN * D;                   // NN*128 bf16
    float*  cnt  = (float*)(h + (size_t)NN * D);          // NN*4 f32
    int*    off  = (int*)(cnt + (size_t)NN * NREL);       // NN+1
    int*    fill = off + (NN + 1);                        // NN
    int*    bsum = fill + NN;                             // 128
    int2*   epk  = (int2*)(bsum + 136);                   // NE records (8B aligned)

    // ---- prep (shared by both layers) ----
    {
        const int S = (NN * NREL) / 4 + NN / 4 + (NN * D) / 4 + KCAT * D + KCAT * DOUT2;
        prep0<<<(S + 255) / 256, 256, 0, stream>>>(x, Xb, W1, root1, Wp1,
                                                   W2, root2, Wp2, cnt, fill);
    }
    count_deg<<<(NE + 255) / 256, 256, 0, stream>>>(dstp, et, cnt);
    scan1<<<SCAN_B, 256, 0, stream>>>(cnt, bsum);
    scan2<<<1, 128, 0, stream>>>(bsum);
    scan3<<<SCAN_B, 256, 0, stream>>>(cnt, bsum, off);
    bucket_edges<<<(NE + 255) / 256, 256, 0, stream>>>(srcp, dstp, et, off, fill,
                                                       epk, cnt);

    const int fblocks = NN / 32;  // 3125 (exact)

    // ---- Layer 1: h = relu(agg(x) @ W1cat + b1), bf16 out ----
    rgcn_fused<128, true, true><<<fblocks, 256, 0, stream>>>(
        Xb, epk, off, Wp1, b1, h, NN);
    // ---- Layer 2: out = agg(h) @ W2cat + b2, f32 out ----
    rgcn_fused<96, false, false><<<fblocks, 256, 0, stream>>>(
        h, epk, off, Wp2, b2, out, NN);
}

// Round 3
// 340.994 us; speedup vs baseline: 1.0724x; 1.0724x over previous
//
#include <hip/hip_runtime.h>

// Problem constants
#define NN 100000      // nodes
#define NE 600000      // edges
#define D  128         // feature dim in (both layers)
#define DOUT2 96
#define NREL 4
#define KREL 512       // NREL * D
#define KCAT 640       // KREL + D
#define SCAN_B 98      // ceil(NN / 1024)

typedef short short8 __attribute__((ext_vector_type(8)));   // 8 bf16
typedef float f32x4  __attribute__((ext_vector_type(4)));
typedef float f32x2  __attribute__((ext_vector_type(2)));

// fp32 -> bf16 round-to-nearest-even (finite inputs)
__device__ __forceinline__ ushort f2bf(float x) {
    unsigned u = __builtin_bit_cast(unsigned, x);
    u += 0x7fffu + ((u >> 16) & 1u);
    return (ushort)(u >> 16);
}
// unpack 2 bf16 (lo,hi of one u32) -> f32x2, for v_pk_fma_f32 accumulate
__device__ __forceinline__ f32x2 bfpair(unsigned u) {
    f32x2 r;
    r.x = __builtin_bit_cast(float, u << 16);
    r.y = __builtin_bit_cast(float, u & 0xffff0000u);
    return r;
}

// ---------------------------------------------------------------------------
// Fused independent prep: zero cnt, zero fill, x->bf16, pack Wcp1, pack Wcp2.
__global__ void prep0(const float* __restrict__ x, ushort* __restrict__ Xb,
                      const float* __restrict__ W1, const float* __restrict__ root1,
                      short* __restrict__ Wp1,
                      const float* __restrict__ W2, const float* __restrict__ root2,
                      short* __restrict__ Wp2,
                      float* __restrict__ cnt, int* __restrict__ fill) {
    int i = blockIdx.x * 256 + threadIdx.x;
    const int S0 = (NN * NREL) / 4;   // 100000 float4 zeros of cnt
    const int S1 = NN / 4;            // 25000 int4 zeros of fill
    const int S2 = (NN * D) / 4;      // 3200000 float4->ushort4 converts
    const int S3 = KCAT * D;          // 81920 pack1 elements
    const int S4 = KCAT * DOUT2;      // 61440 pack2 elements
    if (i < S0) { ((float4*)cnt)[i] = make_float4(0.f, 0.f, 0.f, 0.f); return; }
    i -= S0;
    if (i < S1) { ((int4*)fill)[i] = make_int4(0, 0, 0, 0); return; }
    i -= S1;
    if (i < S2) {
        float4 v = ((const float4*)x)[i];
        ushort4 o;
        o.x = f2bf(v.x); o.y = f2bf(v.y); o.z = f2bf(v.z); o.w = f2bf(v.w);
        ((ushort4*)Xb)[i] = o;
        return;
    }
    i -= S2;
    if (i < S3) {   // Wcp[kq][n][j] = Wcat[kq*8+j][n], BN = 128
        int j = i & 7, rest = i >> 3;
        int n = rest % D, kq = rest / D;
        int k = kq * 8 + j;
        float v = (k < KREL) ? W1[(size_t)k * D + n] : root1[(size_t)(k - KREL) * D + n];
        Wp1[i] = (short)f2bf(v);
        return;
    }
    i -= S3;
    if (i < S4) {   // BN = 96
        int j = i & 7, rest = i >> 3;
        int n = rest % DOUT2, kq = rest / DOUT2;
        int k = kq * 8 + j;
        float v = (k < KREL) ? W2[(size_t)k * DOUT2 + n] : root2[(size_t)(k - KREL) * DOUT2 + n];
        Wp2[i] = (short)f2bf(v);
        return;
    }
}

// ---------------------------------------------------------------------------
// cnt[v][r] = #edges with dst=v, etype=r
__global__ void count_deg(const int* __restrict__ dst,
                          const int* __restrict__ et,
                          float* __restrict__ cnt) {
    int e = blockIdx.x * blockDim.x + threadIdx.x;
    if (e < NE) unsafeAtomicAdd(&cnt[dst[e] * NREL + et[e]], 1.0f);
}

// ---------------------------------------------------------------------------
// Prefix sum of per-node degree -> off[0..NN] (3-kernel scan)
__global__ void scan1(const float* __restrict__ cnt, int* __restrict__ bsum) {
    __shared__ int s[256];
    int tid = threadIdx.x;
    int base = blockIdx.x * 1024 + tid * 4;
    int t = 0;
    for (int i = 0; i < 4; i++) {
        int v = base + i;
        if (v < NN) {
            float4 c = *(const float4*)&cnt[(size_t)v * 4];
            t += (int)(c.x + c.y + c.z + c.w);
        }
    }
    s[tid] = t; __syncthreads();
    for (int o = 128; o > 0; o >>= 1) {
        if (tid < o) s[tid] += s[tid + o];
        __syncthreads();
    }
    if (tid == 0) bsum[blockIdx.x] = s[0];
}

__global__ void scan2(int* __restrict__ bsum) {  // 1 block of 128; exclusive in-place
    __shared__ int s[128];
    int tid = threadIdx.x;
    int mine = (tid < SCAN_B) ? bsum[tid] : 0;
    s[tid] = mine; __syncthreads();
    for (int o = 1; o < 128; o <<= 1) {
        int v = (tid >= o) ? s[tid - o] : 0;
        __syncthreads();
        s[tid] += v;
        __syncthreads();
    }
    if (tid < SCAN_B) bsum[tid] = s[tid] - mine;
}

__global__ void scan3(const float* __restrict__ cnt, const int* __restrict__ bsum,
                      int* __restrict__ off) {
    __shared__ int s[256];
    int tid = threadIdx.x;
    int base = blockIdx.x * 1024 + tid * 4;
    int d[4]; int t = 0;
    for (int i = 0; i < 4; i++) {
        int v = base + i; d[i] = 0;
        if (v < NN) {
            float4 c = *(const float4*)&cnt[(size_t)v * 4];
            d[i] = (int)(c.x + c.y + c.z + c.w);
        }
        t += d[i];
    }
    int mine = t;
    s[tid] = t; __syncthreads();
    for (int o = 1; o < 256; o <<= 1) {
        int v = (tid >= o) ? s[tid - o] : 0;
        __syncthreads();
        s[tid] += v;
        __syncthreads();
    }
    int ex = s[tid] - mine + bsum[blockIdx.x];
    for (int i = 0; i < 4; i++) {
        int v = base + i;
        if (v < NN) { off[v] = ex; ex += d[i]; }
    }
    if (blockIdx.x == 0 && tid == 0) off[NN] = NE;
}

// ---------------------------------------------------------------------------
// Bucket edges by dst; record = { (src<<2)|etype, bitcast(norm) } so the
// fused kernel's inner loop does ONE dwordx2 load per edge and never
// touches cnt / rcp.
__global__ void bucket_edges(const int* __restrict__ src, const int* __restrict__ dst,
                             const int* __restrict__ et, const int* __restrict__ off,
                             int* __restrict__ fill, int2* __restrict__ epk,
                             const float* __restrict__ cnt) {
    int e = blockIdx.x * blockDim.x + threadIdx.x;
    if (e >= NE) return;
    int dn = dst[e];
    int t  = et[e];
    int pos = off[dn] + atomicAdd(&fill[dn], 1);
    float nrm = 1.0f / fmaxf(cnt[dn * NREL + t], 1.0f);   // cnt >= 1 for a real edge
    epk[pos] = make_int2((src[e] << 2) | t, __builtin_bit_cast(int, nrm));
}

// ---------------------------------------------------------------------------
// Fused RGCN layer — block-shared A-tile version.
// Block = 256 threads (4 waves), 32 dst nodes, one 32 KB LDS tile
// [kq16=64][node=32][8 bf16] (MFMA A-frag order), node index XOR-swizzled
// with kq&7 so the staging ds_write_b128 is 2-way (free) instead of 16-way.
//   Phase 1: 16 quarter-wave chains; chain g aggregates nodes v0+g, v0+g+16.
//            4-wide gather batches ONLY (8-wide spilled to scratch in R2:
//            WRITE_SIZE 30->109 MB, dur 82->107 us — keep live set <= alloc),
//            clamped 3-slot tail batch; f32x2 (v_pk_fma_f32) accumulate with
//            per-edge precomputed norm.
//   Root MFMAs (global-only operands) run BEFORE the barrier to overlap
//            the chain-imbalance tail.
//   Phase 2 (after one barrier): wave w computes quadrant
//            (m-half = w&1, n-half = w>>1): 16 nodes x NFW*16 cols.
template <int BN, bool RELU, bool OUT_BF16>
__global__ __launch_bounds__(256, 5) void rgcn_fused(
    const ushort* __restrict__ Xb,   // [M,128] bf16
    const int2*  __restrict__ epk,   // [NE] bucketed {(src<<2)|t, norm}
    const int*   __restrict__ off,   // [M+1]
    const short* __restrict__ Wcp,   // [80][BN][8] bf16
    const float* __restrict__ bias,  // [BN]
    void*        __restrict__ Cout,  // [M,BN] bf16 or f32
    int M) {
    constexpr int NFW = (BN / 16 + 1) / 2;   // frags per wave: 4 (BN=128) / 3 (BN=96)
    __shared__ short At[64 * 32 * 8];        // 32 KB

    const int tid  = threadIdx.x;
    const int wave = tid >> 6;
    const int lane = tid & 63;
    const int l    = lane & 15;     // phase1: feat group / phase2: m16
    const int qw   = lane >> 4;     // phase1: quarter / phase2: k-quad q
    const int g    = wave * 4 + qw; // chain id 0..15
    const int v0   = blockIdx.x * 32;

    // ---- phase 1: aggregate 32 nodes (2 per chain) ----
#pragma unroll
    for (int hf = 0; hf < 2; hf++) {
        int nv = g + hf * 16;
        int v  = v0 + nv;           // NN % 32 == 0 -> always < M
        f32x2 acc[4][4];            // [rel][feat-pair]
#pragma unroll
        for (int r = 0; r < 4; r++)
#pragma unroll
            for (int k = 0; k < 4; k++) acc[r][k] = (f32x2)0.0f;

        int e = off[v], end = off[v + 1];

#define EDGE_ACC(PK, SF, XB) {                                              \
        int t_ = (PK) & 3;                                                  \
        float s0_ = (t_ == 0) ? (SF) : 0.0f;                                \
        float s1_ = (t_ == 1) ? (SF) : 0.0f;                                \
        float s2_ = (t_ == 2) ? (SF) : 0.0f;                                \
        float s3_ = (t_ == 3) ? (SF) : 0.0f;                                \
        f32x2 xp_;                                                          \
        xp_ = bfpair((XB).x);                                               \
        acc[0][0] += s0_ * xp_; acc[1][0] += s1_ * xp_;                     \
        acc[2][0] += s2_ * xp_; acc[3][0] += s3_ * xp_;                     \
        xp_ = bfpair((XB).y);                                               \
        acc[0][1] += s0_ * xp_; acc[1][1] += s1_ * xp_;                     \
        acc[2][1] += s2_ * xp_; acc[3][1] += s3_ * xp_;                     \
        xp_ = bfpair((XB).z);                                               \
        acc[0][2] += s0_ * xp_; acc[1][2] += s1_ * xp_;                     \
        acc[2][2] += s2_ * xp_; acc[3][2] += s3_ * xp_;                     \
        xp_ = bfpair((XB).w);                                               \
        acc[0][3] += s0_ * xp_; acc[1][3] += s1_ * xp_;                     \
        acc[2][3] += s2_ * xp_; acc[3][3] += s3_ * xp_; }

        // 4-wide batches: 4 gathers in flight, live set fits the allocation
        for (; e + 3 < end; e += 4) {
            int2 ep[4];
#pragma unroll
            for (int k = 0; k < 4; k++) ep[k] = epk[e + k];
            uint4 xv[4];
#pragma unroll
            for (int k = 0; k < 4; k++)
                xv[k] = *(const uint4*)&Xb[(size_t)(ep[k].x >> 2) * D + l * 8];
#pragma unroll
            for (int k = 0; k < 4; k++)
                EDGE_ACC(ep[k].x, __builtin_bit_cast(float, ep[k].y), xv[k]);
        }
        // clamped tail batch (1..3 edges, zero-scale on clamped slots):
        // all gathers issue together instead of serial per-edge round-trips
        if (e < end) {
            int rem = end - e;
            int ea = e + (rem > 1);
            int eb = e + ((rem > 2) ? 2 : 0);
            int2 e0 = epk[e], e1 = epk[ea], e2 = epk[eb];
            float f0 = __builtin_bit_cast(float, e0.y);
            float f1 = (rem > 1) ? __builtin_bit_cast(float, e1.y) : 0.0f;
            float f2 = (rem > 2) ? __builtin_bit_cast(float, e2.y) : 0.0f;
            uint4 x0 = *(const uint4*)&Xb[(size_t)(e0.x >> 2) * D + l * 8];
            uint4 x1 = *(const uint4*)&Xb[(size_t)(e1.x >> 2) * D + l * 8];
            uint4 x2 = *(const uint4*)&Xb[(size_t)(e2.x >> 2) * D + l * 8];
            EDGE_ACC(e0.x, f0, x0); EDGE_ACC(e1.x, f1, x1); EDGE_ACC(e2.x, f2, x2);
        }
#undef EDGE_ACC

        // stage to LDS in A-frag order: kq16 = r*16 + l, node nv,
        // node index XOR-swizzled by kq&7 (== l&7): write is 2-way, free.
#pragma unroll
        for (int r = 0; r < 4; r++) {
            short8 w;
#pragma unroll
            for (int k = 0; k < 4; k++) {
                w[2 * k]     = (short)f2bf(acc[r][k].x);
                w[2 * k + 1] = (short)f2bf(acc[r][k].y);
            }
            int kq = r * 16 + l;
            *(short8*)&At[(kq * 32 + (nv ^ (kq & 7))) * 8] = w;
        }
    }

    // ---- phase 2 setup ----
    const int m16   = l;
    const int q     = qw;
    const int mt    = wave & 1;                 // m-half (16 nodes)
    const int nbase = (wave >> 1) * NFW * 16;   // n-offset
    f32x4 acc2[NFW];
#pragma unroll
    for (int i = 0; i < NFW; i++) acc2[i] = (f32x4)0.0f;

    // root part first (k = 512..639, global-only operands): overlaps the
    // barrier wait on slow chains instead of idling.
    {
        int rowc = v0 + mt * 16 + m16;
        const ushort* Xrow = Xb + (size_t)rowc * D;
#pragma unroll
        for (int s2 = 0; s2 < 4; s2++) {
            short8 af = *(const short8*)&Xrow[s2 * 32 + q * 8];
            const short* bbase = Wcp + ((size_t)((16 + s2) * 4 + q) * BN + nbase + m16) * 8;
#pragma unroll
            for (int nf = 0; nf < NFW; nf++) {
                short8 bf = *(const short8*)(bbase + nf * 128);
                acc2[nf] = __builtin_amdgcn_mfma_f32_16x16x32_bf16(af, bf, acc2[nf], 0, 0, 0);
            }
        }
    }

    __syncthreads();

    // ---- phase 2: 32x512 @ 512xBN from LDS, one quadrant per wave ----
#pragma unroll 4
    for (int ks = 0; ks < 16; ks++) {
        int kq = ks * 4 + q;
        short8 af = *(const short8*)&At[(kq * 32 + ((mt * 16 + m16) ^ (kq & 7))) * 8];
        const short* bbase = Wcp + ((size_t)kq * BN + nbase + m16) * 8;
#pragma unroll
        for (int nf = 0; nf < NFW; nf++) {
            short8 bf = *(const short8*)(bbase + nf * 128);
            acc2[nf] = __builtin_amdgcn_mfma_f32_16x16x32_bf16(af, bf, acc2[nf], 0, 0, 0);
        }
    }

    // ---- epilogue ----
#pragma unroll
    for (int nf = 0; nf < NFW; nf++) {
        int n = nbase + nf * 16 + m16;
        float b = bias[n];
#pragma unroll
        for (int r = 0; r < 4; r++) {
            int m = v0 + mt * 16 + q * 4 + r;
            float vv = acc2[nf][r] + b;
            if (RELU) vv = fmaxf(vv, 0.0f);
            if (OUT_BF16) ((ushort*)Cout)[(size_t)m * BN + n] = f2bf(vv);
            else          ((float*)Cout)[(size_t)m * BN + n]  = vv;
        }
    }
}

// ---------------------------------------------------------------------------
extern "C" void kernel_launch(void* const* d_in, const int* in_sizes, int n_in,
                              void* d_out, int out_size, void* d_ws, size_t ws_size,
                              hipStream_t stream) {
    const float* x     = (const float*)d_in[0];
    const int*   ei    = (const int*)d_in[1];
    const int*   et    = (const int*)d_in[2];
    const float* W1    = (const float*)d_in[3];
    const float* root1 = (const float*)d_in[4];
    const float* b1    = (const float*)d_in[5];
    const float* W2    = (const float*)d_in[6];
    const float* root2 = (const float*)d_in[7];
    const float* b2    = (const float*)d_in[8];
    const int* srcp = ei;
    const int* dstp = ei + NE;
    float* out = (float*)d_out;

    // Workspace layout (all segments 16-B aligned)
    short*  Wp1  = (short*)d_ws;                          // 640*128 bf16
    short*  Wp2  = Wp1 + (size_t)KCAT * D;                // 640*96  bf16
    ushort* Xb   = (ushort*)(Wp2 + (size_t)KCAT * DOUT2); // NN*128 bf16
    ushort* h    = Xb + (size_t)NN * D;                   // NN*128 bf16
    float*  cnt  = (float*)(h + (size_t)NN * D);          // NN*4 f32
    int*    off  = (int*)(cnt + (size_t)NN * NREL);       // NN+1
    int*    fill = off + (NN + 1);                        // NN
    int*    bsum = fill + NN;                             // 128
    int2*   epk  = (int2*)(bsum + 136);                   // NE records (8B aligned)

    // ---- prep (shared by both layers) ----
    {
        const int S = (NN * NREL) / 4 + NN / 4 + (NN * D) / 4 + KCAT * D + KCAT * DOUT2;
        prep0<<<(S + 255) / 256, 256, 0, stream>>>(x, Xb, W1, root1, Wp1,
                                                   W2, root2, Wp2, cnt, fill);
    }
    count_deg<<<(NE + 255) / 256, 256, 0, stream>>>(dstp, et, cnt);
    scan1<<<SCAN_B, 256, 0, stream>>>(cnt, bsum);
    scan2<<<1, 128, 0, stream>>>(bsum);
    scan3<<<SCAN_B, 256, 0, stream>>>(cnt, bsum, off);
    bucket_edges<<<(NE + 255) / 256, 256, 0, stream>>>(srcp, dstp, et, off, fill,
                                                       epk, cnt);

    const int fblocks = NN / 32;  // 3125 (exact)

    // ---- Layer 1: h = relu(agg(x) @ W1cat + b1), bf16 out ----
    rgcn_fused<128, true, true><<<fblocks, 256, 0, stream>>>(
        Xb, epk, off, Wp1, b1, h, NN);
    // ---- Layer 2: out = agg(h) @ W2cat + b2, f32 out ----
    rgcn_fused<96, false, false><<<fblocks, 256, 0, stream>>>(
        h, epk, off, Wp2, b2, out, NN);
}

// Round 5
// 324.551 us; speedup vs baseline: 1.1267x; 1.0507x over previous
//
#include <hip/hip_runtime.h>

// Problem constants
#define NN 100000      // nodes
#define NE 600000      // edges
#define D  128         // feature dim in (both layers)
#define DOUT2 96
#define NREL 4
#define KREL 512       // NREL * D
#define KCAT 640       // KREL + D
#define SCAN_B 98      // ceil(NN / 1024)

typedef short short8 __attribute__((ext_vector_type(8)));   // 8 bf16
typedef float f32x4  __attribute__((ext_vector_type(4)));

// fp32 -> bf16 round-to-nearest-even (finite inputs)
__device__ __forceinline__ ushort f2bf(float x) {
    unsigned u = __builtin_bit_cast(unsigned, x);
    u += 0x7fffu + ((u >> 16) & 1u);
    return (ushort)(u >> 16);
}
__device__ __forceinline__ float bfhi(unsigned u) {
    return __builtin_bit_cast(float, u & 0xffff0000u);
}
__device__ __forceinline__ float bflo(unsigned u) {
    return __builtin_bit_cast(float, u << 16);
}

// ---------------------------------------------------------------------------
// Fused independent prep: zero cnt, zero fill, x->bf16, pack Wcp1, pack Wcp2.
__global__ void prep0(const float* __restrict__ x, ushort* __restrict__ Xb,
                      const float* __restrict__ W1, const float* __restrict__ root1,
                      short* __restrict__ Wp1,
                      const float* __restrict__ W2, const float* __restrict__ root2,
                      short* __restrict__ Wp2,
                      float* __restrict__ cnt, int* __restrict__ fill) {
    int i = blockIdx.x * 256 + threadIdx.x;
    const int S0 = (NN * NREL) / 4;   // 100000 float4 zeros of cnt
    const int S1 = NN / 4;            // 25000 int4 zeros of fill
    const int S2 = (NN * D) / 4;      // 3200000 float4->ushort4 converts
    const int S3 = KCAT * D;          // 81920 pack1 elements
    const int S4 = KCAT * DOUT2;      // 61440 pack2 elements
    if (i < S0) { ((float4*)cnt)[i] = make_float4(0.f, 0.f, 0.f, 0.f); return; }
    i -= S0;
    if (i < S1) { ((int4*)fill)[i] = make_int4(0, 0, 0, 0); return; }
    i -= S1;
    if (i < S2) {
        float4 v = ((const float4*)x)[i];
        ushort4 o;
        o.x = f2bf(v.x); o.y = f2bf(v.y); o.z = f2bf(v.z); o.w = f2bf(v.w);
        ((ushort4*)Xb)[i] = o;
        return;
    }
    i -= S2;
    if (i < S3) {   // Wcp[kq][n][j] = Wcat[kq*8+j][n], BN = 128
        int j = i & 7, rest = i >> 3;
        int n = rest % D, kq = rest / D;
        int k = kq * 8 + j;
        float v = (k < KREL) ? W1[(size_t)k * D + n] : root1[(size_t)(k - KREL) * D + n];
        Wp1[i] = (short)f2bf(v);
        return;
    }
    i -= S3;
    if (i < S4) {   // BN = 96
        int j = i & 7, rest = i >> 3;
        int n = rest % DOUT2, kq = rest / DOUT2;
        int k = kq * 8 + j;
        float v = (k < KREL) ? W2[(size_t)k * DOUT2 + n] : root2[(size_t)(k - KREL) * DOUT2 + n];
        Wp2[i] = (short)f2bf(v);
        return;
    }
}

// ---------------------------------------------------------------------------
// cnt[v][r] = #edges with dst=v, etype=r
__global__ void count_deg(const int* __restrict__ dst,
                          const int* __restrict__ et,
                          float* __restrict__ cnt) {
    int e = blockIdx.x * blockDim.x + threadIdx.x;
    if (e < NE) unsafeAtomicAdd(&cnt[dst[e] * NREL + et[e]], 1.0f);
}

// ---------------------------------------------------------------------------
// Prefix sum of per-node degree -> off[0..NN] (3-kernel scan)
__global__ void scan1(const float* __restrict__ cnt, int* __restrict__ bsum) {
    __shared__ int s[256];
    int tid = threadIdx.x;
    int base = blockIdx.x * 1024 + tid * 4;
    int t = 0;
    for (int i = 0; i < 4; i++) {
        int v = base + i;
        if (v < NN) {
            float4 c = *(const float4*)&cnt[(size_t)v * 4];
            t += (int)(c.x + c.y + c.z + c.w);
        }
    }
    s[tid] = t; __syncthreads();
    for (int o = 128; o > 0; o >>= 1) {
        if (tid < o) s[tid] += s[tid + o];
        __syncthreads();
    }
    if (tid == 0) bsum[blockIdx.x] = s[0];
}

__global__ void scan2(int* __restrict__ bsum) {  // 1 block of 128; exclusive in-place
    __shared__ int s[128];
    int tid = threadIdx.x;
    int mine = (tid < SCAN_B) ? bsum[tid] : 0;
    s[tid] = mine; __syncthreads();
    for (int o = 1; o < 128; o <<= 1) {
        int v = (tid >= o) ? s[tid - o] : 0;
        __syncthreads();
        s[tid] += v;
        __syncthreads();
    }
    if (tid < SCAN_B) bsum[tid] = s[tid] - mine;
}

__global__ void scan3(const float* __restrict__ cnt, const int* __restrict__ bsum,
                      int* __restrict__ off) {
    __shared__ int s[256];
    int tid = threadIdx.x;
    int base = blockIdx.x * 1024 + tid * 4;
    int d[4]; int t = 0;
    for (int i = 0; i < 4; i++) {
        int v = base + i; d[i] = 0;
        if (v < NN) {
            float4 c = *(const float4*)&cnt[(size_t)v * 4];
            d[i] = (int)(c.x + c.y + c.z + c.w);
        }
        t += d[i];
    }
    int mine = t;
    s[tid] = t; __syncthreads();
    for (int o = 1; o < 256; o <<= 1) {
        int v = (tid >= o) ? s[tid - o] : 0;
        __syncthreads();
        s[tid] += v;
        __syncthreads();
    }
    int ex = s[tid] - mine + bsum[blockIdx.x];
    for (int i = 0; i < 4; i++) {
        int v = base + i;
        if (v < NN) { off[v] = ex; ex += d[i]; }
    }
    if (blockIdx.x == 0 && tid == 0) off[NN] = NE;
}

// ---------------------------------------------------------------------------
// Bucket edges by dst; packed (src<<2)|etype
__global__ void bucket_edges(const int* __restrict__ src, const int* __restrict__ dst,
                             const int* __restrict__ et, const int* __restrict__ off,
                             int* __restrict__ fill, int* __restrict__ srcpk) {
    int e = blockIdx.x * blockDim.x + threadIdx.x;
    if (e >= NE) return;
    int dn = dst[e];
    int pos = off[dn] + atomicAdd(&fill[dn], 1);
    srcpk[pos] = (src[e] << 2) | et[e];
}

// ---------------------------------------------------------------------------
// Fused RGCN layer — block-shared A-tile version (R0 register structure:
// 48 VGPR, zero spill — measured WRITE_SIZE == output size).
// Block = 256 threads (4 waves), 32 dst nodes, one 32 KB LDS tile
// [kq16=64][node=32][8 bf16] (MFMA A-frag order). Node slot XOR-swizzled
// by kq&7: staging ds_write_b128 spreads uniformly over all 32 banks
// (measured: SQ_LDS_BANK_CONFLICT 5.6M -> 0). 5 blocks/CU (LDS-capped).
//   Phase 1: 16 quarter-wave chains; chain g aggregates nodes v0+g, v0+g+16
//            (full per-node edge range, 4-edge unrolled gathers, fp32 acc
//            with predicated per-relation scales). DO NOT widen the batch
//            or add live temps: allocator pins 48 VGPR and spills the rest
//            (R2/R3: +43..79 MB HBM write, dur +10..25 us).
//   Root MFMAs (global-only operands) run BEFORE the barrier so fast waves
//            overlap the chain-imbalance tail.
//   Phase 2 (after one barrier): wave w computes quadrant
//            (m-half = w&1, n-half = w>>1): 16 nodes x NFW*16 cols.
template <int BN, bool RELU, bool OUT_BF16>
__global__ __launch_bounds__(256, 5) void rgcn_fused(
    const ushort* __restrict__ Xb,   // [M,128] bf16
    const int*   __restrict__ srcpk, // [NE] bucketed, (src<<2)|t
    const int*   __restrict__ off,   // [M+1]
    const float* __restrict__ cnt,   // [M,4]
    const short* __restrict__ Wcp,   // [80][BN][8] bf16
    const float* __restrict__ bias,  // [BN]
    void*        __restrict__ Cout,  // [M,BN] bf16 or f32
    int M) {
    constexpr int NFW = (BN / 16 + 1) / 2;   // frags per wave: 4 (BN=128) / 3 (BN=96)
    __shared__ short At[64 * 32 * 8];        // 32 KB

    const int tid  = threadIdx.x;
    const int wave = tid >> 6;
    const int lane = tid & 63;
    const int l    = lane & 15;     // phase1: feat group / phase2: m16
    const int qw   = lane >> 4;     // phase1: quarter / phase2: k-quad q
    const int g    = wave * 4 + qw; // chain id 0..15
    const int v0   = blockIdx.x * 32;

    // ---- phase 1: aggregate 32 nodes (2 per chain) ----
#pragma unroll
    for (int half = 0; half < 2; half++) {
        int nv = g + half * 16;
        int v  = v0 + nv;           // NN % 32 == 0 -> always < M
        float acc[4][8];
#pragma unroll
        for (int r = 0; r < 4; r++)
#pragma unroll
            for (int j = 0; j < 8; j++) acc[r][j] = 0.0f;

        float4 c4 = *(const float4*)&cnt[(size_t)v * 4];
        float nrm0 = 1.0f / fmaxf(c4.x, 1.0f);
        float nrm1 = 1.0f / fmaxf(c4.y, 1.0f);
        float nrm2 = 1.0f / fmaxf(c4.z, 1.0f);
        float nrm3 = 1.0f / fmaxf(c4.w, 1.0f);
        int e = off[v], end = off[v + 1];

#define EDGE_ACC(PK, XB) {                                                  \
        int t_ = (PK) & 3;                                                  \
        float s0 = (t_ == 0) ? nrm0 : 0.0f;                                 \
        float s1 = (t_ == 1) ? nrm1 : 0.0f;                                 \
        float s2 = (t_ == 2) ? nrm2 : 0.0f;                                 \
        float s3 = (t_ == 3) ? nrm3 : 0.0f;                                 \
        float xf[8];                                                        \
        xf[0] = bflo(XB.x); xf[1] = bfhi(XB.x);                             \
        xf[2] = bflo(XB.y); xf[3] = bfhi(XB.y);                             \
        xf[4] = bflo(XB.z); xf[5] = bfhi(XB.z);                             \
        xf[6] = bflo(XB.w); xf[7] = bfhi(XB.w);                             \
        _Pragma("unroll")                                                   \
        for (int j = 0; j < 8; j++) {                                       \
            acc[0][j] += s0 * xf[j];                                        \
            acc[1][j] += s1 * xf[j];                                        \
            acc[2][j] += s2 * xf[j];                                        \
            acc[3][j] += s3 * xf[j];                                        \
        } }

        for (; e + 3 < end; e += 4) {   // 4 gathers in flight per chain
            int p0 = srcpk[e],     p1 = srcpk[e + 1];
            int p2 = srcpk[e + 2], p3 = srcpk[e + 3];
            uint4 x0 = *(const uint4*)&Xb[(size_t)(p0 >> 2) * D + l * 8];
            uint4 x1 = *(const uint4*)&Xb[(size_t)(p1 >> 2) * D + l * 8];
            uint4 x2 = *(const uint4*)&Xb[(size_t)(p2 >> 2) * D + l * 8];
            uint4 x3 = *(const uint4*)&Xb[(size_t)(p3 >> 2) * D + l * 8];
            EDGE_ACC(p0, x0); EDGE_ACC(p1, x1);
            EDGE_ACC(p2, x2); EDGE_ACC(p3, x3);
        }
        for (; e < end; e++) {
            int p0 = srcpk[e];
            uint4 x0 = *(const uint4*)&Xb[(size_t)(p0 >> 2) * D + l * 8];
            EDGE_ACC(p0, x0);
        }
#undef EDGE_ACC

        // stage to LDS in A-frag order: kq16 = r*16 + l, node slot XOR-swizzled
        // by kq&7 -> ds_write_b128 uniform over 32 banks (measured 0 conflicts)
#pragma unroll
        for (int r = 0; r < 4; r++) {
            short8 w;
#pragma unroll
            for (int j = 0; j < 8; j++) w[j] = (short)f2bf(acc[r][j]);
            int kq = r * 16 + l;
            *(short8*)&At[(kq * 32 + (nv ^ (kq & 7))) * 8] = w;
        }
    }

    // ---- phase 2 setup ----
    const int m16   = l;
    const int q     = qw;
    const int mt    = wave & 1;           // m-half (16 nodes)
    const int nbase = (wave >> 1) * NFW * 16;   // n-offset
    f32x4 acc2[NFW];
#pragma unroll
    for (int i = 0; i < NFW; i++) acc2[i] = (f32x4)0.0f;

    // root part first (k = 512..639, global-only operands): phase-1 registers
    // are dead here, so this adds no pressure; fast waves do these MFMAs
    // while slow chains finish gathering (overlaps the barrier wait).
    {
        int rowc = v0 + mt * 16 + m16;
        const ushort* Xrow = Xb + (size_t)rowc * D;
#pragma unroll
        for (int s2 = 0; s2 < 4; s2++) {
            short8 af = *(const short8*)&Xrow[s2 * 32 + q * 8];
            const short* bbase = Wcp + ((size_t)((16 + s2) * 4 + q) * BN + nbase + m16) * 8;
#pragma unroll
            for (int nf = 0; nf < NFW; nf++) {
                short8 bf = *(const short8*)(bbase + nf * 128);
                acc2[nf] = __builtin_amdgcn_mfma_f32_16x16x32_bf16(af, bf, acc2[nf], 0, 0, 0);
            }
        }
    }

    __syncthreads();

    // ---- phase 2: 32x512 @ 512xBN from LDS, one quadrant per wave ----
#pragma unroll 4
    for (int ks = 0; ks < 16; ks++) {
        int kq = ks * 4 + q;
        short8 af = *(const short8*)&At[(kq * 32 + ((mt * 16 + m16) ^ (kq & 7))) * 8];
        const short* bbase = Wcp + ((size_t)kq * BN + nbase + m16) * 8;
#pragma unroll
        for (int nf = 0; nf < NFW; nf++) {
            short8 bf = *(const short8*)(bbase + nf * 128);
            acc2[nf] = __builtin_amdgcn_mfma_f32_16x16x32_bf16(af, bf, acc2[nf], 0, 0, 0);
        }
    }

    // ---- epilogue ----
#pragma unroll
    for (int nf = 0; nf < NFW; nf++) {
        int n = nbase + nf * 16 + m16;
        float b = bias[n];
#pragma unroll
        for (int r = 0; r < 4; r++) {
            int m = v0 + mt * 16 + q * 4 + r;
            float vv = acc2[nf][r] + b;
            if (RELU) vv = fmaxf(vv, 0.0f);
            if (OUT_BF16) ((ushort*)Cout)[(size_t)m * BN + n] = f2bf(vv);
            else          ((float*)Cout)[(size_t)m * BN + n]  = vv;
        }
    }
}

// ---------------------------------------------------------------------------
extern "C" void kernel_launch(void* const* d_in, const int* in_sizes, int n_in,
                              void* d_out, int out_size, void* d_ws, size_t ws_size,
                              hipStream_t stream) {
    const float* x     = (const float*)d_in[0];
    const int*   ei    = (const int*)d_in[1];
    const int*   et    = (const int*)d_in[2];
    const float* W1    = (const float*)d_in[3];
    const float* root1 = (const float*)d_in[4];
    const float* b1    = (const float*)d_in[5];
    const float* W2    = (const float*)d_in[6];
    const float* root2 = (const float*)d_in[7];
    const float* b2    = (const float*)d_in[8];
    const int* srcp = ei;
    const int* dstp = ei + NE;
    float* out = (float*)d_out;

    // Workspace layout (all segments 16-B aligned)
    short*  Wp1  = (short*)d_ws;                          // 640*128 bf16
    short*  Wp2  = Wp1 + (size_t)KCAT * D;                // 640*96  bf16
    ushort* Xb   = (ushort*)(Wp2 + (size_t)KCAT * DOUT2); // NN*128 bf16
    ushort* h    = Xb + (size_t)NN * D;                   // NN*128 bf16
    float*  cnt  = (float*)(h + (size_t)NN * D);          // NN*4 f32
    int*    off  = (int*)(cnt + (size_t)NN * NREL);       // NN+1
    int*    fill = off + (NN + 1);                        // NN
    int*    bsum = fill + NN;                             // 128
    int*    srcpk= bsum + 128;                            // NE

    // ---- prep (shared by both layers) ----
    {
        const int S = (NN * NREL) / 4 + NN / 4 + (NN * D) / 4 + KCAT * D + KCAT * DOUT2;
        prep0<<<(S + 255) / 256, 256, 0, stream>>>(x, Xb, W1, root1, Wp1,
                                                   W2, root2, Wp2, cnt, fill);
    }
    count_deg<<<(NE + 255) / 256, 256, 0, stream>>>(dstp, et, cnt);
    scan1<<<SCAN_B, 256, 0, stream>>>(cnt, bsum);
    scan2<<<1, 128, 0, stream>>>(bsum);
    scan3<<<SCAN_B, 256, 0, stream>>>(cnt, bsum, off);
    bucket_edges<<<(NE + 255) / 256, 256, 0, stream>>>(srcp, dstp, et, off, fill, srcpk);

    const int fblocks = NN / 32;  // 3125 (exact)

    // ---- Layer 1: h = relu(agg(x) @ W1cat + b1), bf16 out ----
    rgcn_fused<128, true, true><<<fblocks, 256, 0, stream>>>(
        Xb, srcpk, off, cnt, Wp1, b1, h, NN);
    // ---- Layer 2: out = agg(h) @ W2cat + b2, f32 out ----
    rgcn_fused<96, false, false><<<fblocks, 256, 0, stream>>>(
        h, srcpk, off, cnt, Wp2, b2, out, NN);
}

// Round 6
// 322.336 us; speedup vs baseline: 1.1344x; 1.0069x over previous
//
#include <hip/hip_runtime.h>

// Problem constants
#define NN 100000      // nodes
#define NE 600000      // edges
#define D  128         // feature dim in (both layers)
#define DOUT2 96
#define NREL 4
#define KREL 512       // NREL * D
#define KCAT 640       // KREL + D
#define SCAN_B 98      // ceil(NN / 1024)

typedef short short8 __attribute__((ext_vector_type(8)));   // 8 bf16
typedef float f32x4  __attribute__((ext_vector_type(4)));

// fp32 -> bf16 round-to-nearest-even (finite inputs)
__device__ __forceinline__ ushort f2bf(float x) {
    unsigned u = __builtin_bit_cast(unsigned, x);
    u += 0x7fffu + ((u >> 16) & 1u);
    return (ushort)(u >> 16);
}
__device__ __forceinline__ float bfhi(unsigned u) {
    return __builtin_bit_cast(float, u & 0xffff0000u);
}
__device__ __forceinline__ float bflo(unsigned u) {
    return __builtin_bit_cast(float, u << 16);
}

// ---------------------------------------------------------------------------
// Fused independent prep: zero cnt, zero fill, x->bf16, pack Wcp1, pack Wcp2.
__global__ void prep0(const float* __restrict__ x, ushort* __restrict__ Xb,
                      const float* __restrict__ W1, const float* __restrict__ root1,
                      short* __restrict__ Wp1,
                      const float* __restrict__ W2, const float* __restrict__ root2,
                      short* __restrict__ Wp2,
                      float* __restrict__ cnt, int* __restrict__ fill) {
    int i = blockIdx.x * 256 + threadIdx.x;
    const int S0 = (NN * NREL) / 4;   // 100000 float4 zeros of cnt
    const int S1 = NN / 4;            // 25000 int4 zeros of fill
    const int S2 = (NN * D) / 4;      // 3200000 float4->ushort4 converts
    const int S3 = KCAT * D;          // 81920 pack1 elements
    const int S4 = KCAT * DOUT2;      // 61440 pack2 elements
    if (i < S0) { ((float4*)cnt)[i] = make_float4(0.f, 0.f, 0.f, 0.f); return; }
    i -= S0;
    if (i < S1) { ((int4*)fill)[i] = make_int4(0, 0, 0, 0); return; }
    i -= S1;
    if (i < S2) {
        float4 v = ((const float4*)x)[i];
        ushort4 o;
        o.x = f2bf(v.x); o.y = f2bf(v.y); o.z = f2bf(v.z); o.w = f2bf(v.w);
        ((ushort4*)Xb)[i] = o;
        return;
    }
    i -= S2;
    if (i < S3) {   // Wcp[kq][n][j] = Wcat[kq*8+j][n], BN = 128
        int j = i & 7, rest = i >> 3;
        int n = rest % D, kq = rest / D;
        int k = kq * 8 + j;
        float v = (k < KREL) ? W1[(size_t)k * D + n] : root1[(size_t)(k - KREL) * D + n];
        Wp1[i] = (short)f2bf(v);
        return;
    }
    i -= S3;
    if (i < S4) {   // BN = 96
        int j = i & 7, rest = i >> 3;
        int n = rest % DOUT2, kq = rest / DOUT2;
        int k = kq * 8 + j;
        float v = (k < KREL) ? W2[(size_t)k * DOUT2 + n] : root2[(size_t)(k - KREL) * DOUT2 + n];
        Wp2[i] = (short)f2bf(v);
        return;
    }
}

// ---------------------------------------------------------------------------
// cnt[v][r] = #edges with dst=v, etype=r
__global__ void count_deg(const int* __restrict__ dst,
                          const int* __restrict__ et,
                          float* __restrict__ cnt) {
    int e = blockIdx.x * blockDim.x + threadIdx.x;
    if (e < NE) unsafeAtomicAdd(&cnt[dst[e] * NREL + et[e]], 1.0f);
}

// ---------------------------------------------------------------------------
// Prefix sum of per-node degree -> off[0..NN] (3-kernel scan)
__global__ void scan1(const float* __restrict__ cnt, int* __restrict__ bsum) {
    __shared__ int s[256];
    int tid = threadIdx.x;
    int base = blockIdx.x * 1024 + tid * 4;
    int t = 0;
    for (int i = 0; i < 4; i++) {
        int v = base + i;
        if (v < NN) {
            float4 c = *(const float4*)&cnt[(size_t)v * 4];
            t += (int)(c.x + c.y + c.z + c.w);
        }
    }
    s[tid] = t; __syncthreads();
    for (int o = 128; o > 0; o >>= 1) {
        if (tid < o) s[tid] += s[tid + o];
        __syncthreads();
    }
    if (tid == 0) bsum[blockIdx.x] = s[0];
}

__global__ void scan2(int* __restrict__ bsum) {  // 1 block of 128; exclusive in-place
    __shared__ int s[128];
    int tid = threadIdx.x;
    int mine = (tid < SCAN_B) ? bsum[tid] : 0;
    s[tid] = mine; __syncthreads();
    for (int o = 1; o < 128; o <<= 1) {
        int v = (tid >= o) ? s[tid - o] : 0;
        __syncthreads();
        s[tid] += v;
        __syncthreads();
    }
    if (tid < SCAN_B) bsum[tid] = s[tid] - mine;
}

__global__ void scan3(const float* __restrict__ cnt, const int* __restrict__ bsum,
                      int* __restrict__ off) {
    __shared__ int s[256];
    int tid = threadIdx.x;
    int base = blockIdx.x * 1024 + tid * 4;
    int d[4]; int t = 0;
    for (int i = 0; i < 4; i++) {
        int v = base + i; d[i] = 0;
        if (v < NN) {
            float4 c = *(const float4*)&cnt[(size_t)v * 4];
            d[i] = (int)(c.x + c.y + c.z + c.w);
        }
        t += d[i];
    }
    int mine = t;
    s[tid] = t; __syncthreads();
    for (int o = 1; o < 256; o <<= 1) {
        int v = (tid >= o) ? s[tid - o] : 0;
        __syncthreads();
        s[tid] += v;
        __syncthreads();
    }
    int ex = s[tid] - mine + bsum[blockIdx.x];
    for (int i = 0; i < 4; i++) {
        int v = base + i;
        if (v < NN) { off[v] = ex; ex += d[i]; }
    }
    if (blockIdx.x == 0 && tid == 0) off[NN] = NE;
}

// ---------------------------------------------------------------------------
// Bucket edges by dst; packed (src<<2)|etype
__global__ void bucket_edges(const int* __restrict__ src, const int* __restrict__ dst,
                             const int* __restrict__ et, const int* __restrict__ off,
                             int* __restrict__ fill, int* __restrict__ srcpk) {
    int e = blockIdx.x * blockDim.x + threadIdx.x;
    if (e >= NE) return;
    int dn = dst[e];
    int pos = off[dn] + atomicAdd(&fill[dn], 1);
    srcpk[pos] = (src[e] << 2) | et[e];
}

// ---------------------------------------------------------------------------
// Fused RGCN layer — block-shared A-tile, dynamic node queue.
// Block = 256 threads (4 waves), 32 dst nodes, one 32 KB LDS tile
// [kq16=64][node=32][8 bf16] (MFMA A-frag order), node slot XOR-swizzled
// by kq&7 (measured: SQ_LDS_BANK_CONFLICT 5.6M -> 0; register-free).
//   Phase 1: 16 quarter-wave chains. Chain g takes node v0+g statically,
//            then pulls nodes 16..31 from an LDS atomic queue — phase-1
//            block time drops from max-over-16-chains (~22-24 edges,
//            Poisson(6)/node static 2-node split) toward sum/16 (~16-18).
//            Per-node body is byte-identical to the R0/R5 structure:
//            48 VGPR, zero spill (measured WRITE_SIZE == output). DO NOT
//            widen gather batches or add live temps (R2/R3: scratch spill,
//            +43..79 MB HBM write, dur +10..25 us).
//   Root MFMAs (global-only operands) run BEFORE the barrier.
//   Phase 2 (after one barrier): wave w computes quadrant
//            (m-half = w&1, n-half = w>>1): 16 nodes x NFW*16 cols.
template <int BN, bool RELU, bool OUT_BF16>
__global__ __launch_bounds__(256, 5) void rgcn_fused(
    const ushort* __restrict__ Xb,   // [M,128] bf16
    const int*   __restrict__ srcpk, // [NE] bucketed, (src<<2)|t
    const int*   __restrict__ off,   // [M+1]
    const float* __restrict__ cnt,   // [M,4]
    const short* __restrict__ Wcp,   // [80][BN][8] bf16
    const float* __restrict__ bias,  // [BN]
    void*        __restrict__ Cout,  // [M,BN] bf16 or f32
    int M) {
    constexpr int NFW = (BN / 16 + 1) / 2;   // frags per wave: 4 (BN=128) / 3 (BN=96)
    __shared__ short At[64 * 32 * 8];        // 32 KB
    __shared__ int qctr;                     // node work queue

    const int tid  = threadIdx.x;
    const int wave = tid >> 6;
    const int lane = tid & 63;
    const int l    = lane & 15;     // phase1: feat group / phase2: m16
    const int qw   = lane >> 4;     // phase1: quarter / phase2: k-quad q
    const int g    = wave * 4 + qw; // chain id 0..15
    const int v0   = blockIdx.x * 32;

    if (tid == 0) qctr = 16;        // nodes 0..15 are statically assigned
    __syncthreads();

    // ---- phase 1: chains pull nodes until the block's 32 are done ----
    int nv = g;                     // first node static (no atomic burst)
    while (nv < 32) {
        int v = v0 + nv;            // NN % 32 == 0 -> always < M
        float acc[4][8];
#pragma unroll
        for (int r = 0; r < 4; r++)
#pragma unroll
            for (int j = 0; j < 8; j++) acc[r][j] = 0.0f;

        float4 c4 = *(const float4*)&cnt[(size_t)v * 4];
        float nrm0 = 1.0f / fmaxf(c4.x, 1.0f);
        float nrm1 = 1.0f / fmaxf(c4.y, 1.0f);
        float nrm2 = 1.0f / fmaxf(c4.z, 1.0f);
        float nrm3 = 1.0f / fmaxf(c4.w, 1.0f);
        int e = off[v], end = off[v + 1];

#define EDGE_ACC(PK, XB) {                                                  \
        int t_ = (PK) & 3;                                                  \
        float s0 = (t_ == 0) ? nrm0 : 0.0f;                                 \
        float s1 = (t_ == 1) ? nrm1 : 0.0f;                                 \
        float s2 = (t_ == 2) ? nrm2 : 0.0f;                                 \
        float s3 = (t_ == 3) ? nrm3 : 0.0f;                                 \
        float xf[8];                                                        \
        xf[0] = bflo(XB.x); xf[1] = bfhi(XB.x);                             \
        xf[2] = bflo(XB.y); xf[3] = bfhi(XB.y);                             \
        xf[4] = bflo(XB.z); xf[5] = bfhi(XB.z);                             \
        xf[6] = bflo(XB.w); xf[7] = bfhi(XB.w);                             \
        _Pragma("unroll")                                                   \
        for (int j = 0; j < 8; j++) {                                       \
            acc[0][j] += s0 * xf[j];                                        \
            acc[1][j] += s1 * xf[j];                                        \
            acc[2][j] += s2 * xf[j];                                        \
            acc[3][j] += s3 * xf[j];                                        \
        } }

        for (; e + 3 < end; e += 4) {   // 4 gathers in flight per chain
            int p0 = srcpk[e],     p1 = srcpk[e + 1];
            int p2 = srcpk[e + 2], p3 = srcpk[e + 3];
            uint4 x0 = *(const uint4*)&Xb[(size_t)(p0 >> 2) * D + l * 8];
            uint4 x1 = *(const uint4*)&Xb[(size_t)(p1 >> 2) * D + l * 8];
            uint4 x2 = *(const uint4*)&Xb[(size_t)(p2 >> 2) * D + l * 8];
            uint4 x3 = *(const uint4*)&Xb[(size_t)(p3 >> 2) * D + l * 8];
            EDGE_ACC(p0, x0); EDGE_ACC(p1, x1);
            EDGE_ACC(p2, x2); EDGE_ACC(p3, x3);
        }
        for (; e < end; e++) {
            int p0 = srcpk[e];
            uint4 x0 = *(const uint4*)&Xb[(size_t)(p0 >> 2) * D + l * 8];
            EDGE_ACC(p0, x0);
        }
#undef EDGE_ACC

        // stage to LDS in A-frag order: kq16 = r*16 + l, node slot XOR-swizzled
        // by kq&7 -> ds_write_b128 uniform over 32 banks (measured 0 conflicts)
#pragma unroll
        for (int r = 0; r < 4; r++) {
            short8 w;
#pragma unroll
            for (int j = 0; j < 8; j++) w[j] = (short)f2bf(acc[r][j]);
            int kq = r * 16 + l;
            *(short8*)&At[(kq * 32 + (nv ^ (kq & 7))) * 8] = w;
        }

        // grab next node (lane 0 of the chain, broadcast to the other 15)
        int nn = 32;
        if (l == 0) nn = atomicAdd(&qctr, 1);
        nv = __shfl(nn, lane & 48);
    }

    // ---- phase 2 setup ----
    const int m16   = l;
    const int q     = qw;
    const int mt    = wave & 1;           // m-half (16 nodes)
    const int nbase = (wave >> 1) * NFW * 16;   // n-offset
    f32x4 acc2[NFW];
#pragma unroll
    for (int i = 0; i < NFW; i++) acc2[i] = (f32x4)0.0f;

    // root part first (k = 512..639, global-only operands): phase-1 registers
    // are dead here, so this adds no pressure; fast waves do these MFMAs
    // while slow chains finish gathering (overlaps the barrier wait).
    {
        int rowc = v0 + mt * 16 + m16;
        const ushort* Xrow = Xb + (size_t)rowc * D;
#pragma unroll
        for (int s2 = 0; s2 < 4; s2++) {
            short8 af = *(const short8*)&Xrow[s2 * 32 + q * 8];
            const short* bbase = Wcp + ((size_t)((16 + s2) * 4 + q) * BN + nbase + m16) * 8;
#pragma unroll
            for (int nf = 0; nf < NFW; nf++) {
                short8 bf = *(const short8*)(bbase + nf * 128);
                acc2[nf] = __builtin_amdgcn_mfma_f32_16x16x32_bf16(af, bf, acc2[nf], 0, 0, 0);
            }
        }
    }

    __syncthreads();

    // ---- phase 2: 32x512 @ 512xBN from LDS, one quadrant per wave ----
#pragma unroll 4
    for (int ks = 0; ks < 16; ks++) {
        int kq = ks * 4 + q;
        short8 af = *(const short8*)&At[(kq * 32 + ((mt * 16 + m16) ^ (kq & 7))) * 8];
        const short* bbase = Wcp + ((size_t)kq * BN + nbase + m16) * 8;
#pragma unroll
        for (int nf = 0; nf < NFW; nf++) {
            short8 bf = *(const short8*)(bbase + nf * 128);
            acc2[nf] = __builtin_amdgcn_mfma_f32_16x16x32_bf16(af, bf, acc2[nf], 0, 0, 0);
        }
    }

    // ---- epilogue ----
#pragma unroll
    for (int nf = 0; nf < NFW; nf++) {
        int n = nbase + nf * 16 + m16;
        float b = bias[n];
#pragma unroll
        for (int r = 0; r < 4; r++) {
            int m = v0 + mt * 16 + q * 4 + r;
            float vv = acc2[nf][r] + b;
            if (RELU) vv = fmaxf(vv, 0.0f);
            if (OUT_BF16) ((ushort*)Cout)[(size_t)m * BN + n] = f2bf(vv);
            else          ((float*)Cout)[(size_t)m * BN + n]  = vv;
        }
    }
}

// ---------------------------------------------------------------------------
extern "C" void kernel_launch(void* const* d_in, const int* in_sizes, int n_in,
                              void* d_out, int out_size, void* d_ws, size_t ws_size,
                              hipStream_t stream) {
    const float* x     = (const float*)d_in[0];
    const int*   ei    = (const int*)d_in[1];
    const int*   et    = (const int*)d_in[2];
    const float* W1    = (const float*)d_in[3];
    const float* root1 = (const float*)d_in[4];
    const float* b1    = (const float*)d_in[5];
    const float* W2    = (const float*)d_in[6];
    const float* root2 = (const float*)d_in[7];
    const float* b2    = (const float*)d_in[8];
    const int* srcp = ei;
    const int* dstp = ei + NE;
    float* out = (float*)d_out;

    // Workspace layout (all segments 16-B aligned)
    short*  Wp1  = (short*)d_ws;                          // 640*128 bf16
    short*  Wp2  = Wp1 + (size_t)KCAT * D;                // 640*96  bf16
    ushort* Xb   = (ushort*)(Wp2 + (size_t)KCAT * DOUT2); // NN*128 bf16
    ushort* h    = Xb + (size_t)NN * D;                   // NN*128 bf16
    float*  cnt  = (float*)(h + (size_t)NN * D);          // NN*4 f32
    int*    off  = (int*)(cnt + (size_t)NN * NREL);       // NN+1
    int*    fill = off + (NN + 1);                        // NN
    int*    bsum = fill + NN;                             // 128
    int*    srcpk= bsum + 128;                            // NE

    // ---- prep (shared by both layers) ----
    {
        const int S = (NN * NREL) / 4 + NN / 4 + (NN * D) / 4 + KCAT * D + KCAT * DOUT2;
        prep0<<<(S + 255) / 256, 256, 0, stream>>>(x, Xb, W1, root1, Wp1,
                                                   W2, root2, Wp2, cnt, fill);
    }
    count_deg<<<(NE + 255) / 256, 256, 0, stream>>>(dstp, et, cnt);
    scan1<<<SCAN_B, 256, 0, stream>>>(cnt, bsum);
    scan2<<<1, 128, 0, stream>>>(bsum);
    scan3<<<SCAN_B, 256, 0, stream>>>(cnt, bsum, off);
    bucket_edges<<<(NE + 255) / 256, 256, 0, stream>>>(srcp, dstp, et, off, fill, srcpk);

    const int fblocks = NN / 32;  // 3125 (exact)

    // ---- Layer 1: h = relu(agg(x) @ W1cat + b1), bf16 out ----
    rgcn_fused<128, true, true><<<fblocks, 256, 0, stream>>>(
        Xb, srcpk, off, cnt, Wp1, b1, h, NN);
    // ---- Layer 2: out = agg(h) @ W2cat + b2, f32 out ----
    rgcn_fused<96, false, false><<<fblocks, 256, 0, stream>>>(
        h, srcpk, off, cnt, Wp2, b2, out, NN);
}